// Round 1
// baseline (1788.904 us; speedup 1.0000x reference)
//
#include <hip/hip_runtime.h>
#include <math.h>

#define BD 2
#define SD 1024
#define HIDD 2048
#define NHD 16
#define NSD 8
#define DD 128

// ---------------------------------------------------------------------------
// splat_prep: normalize positions/directions, precompute pos_sq, p·d, 1/(2s^2),
// amplitude softmax. 128 splats total (NH*NS), one thread each.
// ---------------------------------------------------------------------------
__global__ void splat_prep(const float* __restrict__ sp, const float* __restrict__ sd,
                           const float* __restrict__ ls, const float* __restrict__ la,
                           float* __restrict__ posn, float* __restrict__ dirn,
                           float* __restrict__ pos_sq, float* __restrict__ pdv,
                           float* __restrict__ iv2s2, float* __restrict__ amp) {
    int i = threadIdx.x;  // h*8+n, 0..127
    const float* p = sp + (size_t)i * DD;
    const float* d = sd + (size_t)i * DD;
    float np_ = 0.f, nd_ = 0.f;
    for (int k = 0; k < DD; ++k) { np_ += p[k] * p[k]; nd_ += d[k] * d[k]; }
    np_ = sqrtf(np_); nd_ = sqrtf(nd_);
    const float sc = 3.394112549695428f;  // sqrt(128)*0.3
    float rp = sc / (np_ + 1e-12f);
    float rd = 1.f / (nd_ + 1e-12f);
    float psq = 0.f, pd_ = 0.f;
    for (int k = 0; k < DD; ++k) {
        float pn = p[k] * rp;
        float dn = d[k] * rd;
        posn[(size_t)i * DD + k] = pn;
        dirn[(size_t)i * DD + k] = dn;
        psq += pn * pn;
        pd_ += pn * dn;
    }
    pos_sq[i] = psq;
    pdv[i] = pd_;
    float s = expf(ls[i]);
    s = fminf(fmaxf(s, 0.3f), 1.2f);
    iv2s2[i] = 0.5f / (s * s);
    if ((i & 7) == 0) {
        int h = i >> 3;
        float mx = -INFINITY;
        for (int n = 0; n < NSD; ++n) mx = fmaxf(mx, la[h * NSD + n]);
        float e[NSD]; float ssum = 0.f;
        for (int n = 0; n < NSD; ++n) { e[n] = expf(la[h * NSD + n] - mx); ssum += e[n]; }
        for (int n = 0; n < NSD; ++n) amp[h * NSD + n] = e[n] / ssum;
    }
}

// ---------------------------------------------------------------------------
// gemm_tiled: C = A @ W, fp32, M=N=K=2048 fixed. 64x64 tile, BK=32, 4x4/thread.
// headmode=1 scatters output into [B,NH,S,D] head layout; headmode=0 row-major.
// ---------------------------------------------------------------------------
__global__ __launch_bounds__(256) void gemm_tiled(const float* __restrict__ A,
                                                  const float* __restrict__ W,
                                                  float* __restrict__ C, int headmode) {
    __shared__ float As[32][68];  // As[k][m], padded
    __shared__ float Bs[32][68];  // Bs[k][n], padded (68*4B = 17*16B -> f4 aligned)
    const int tid = threadIdx.x;
    const int bm = blockIdx.x * 64, bn = blockIdx.y * 64;
    const int r0 = (tid >> 4) * 4;
    const int c0 = (tid & 15) * 4;
    const int arow = tid >> 3;       // 0..31
    const int ak4 = (tid & 7) * 4;   // 0..28
    const int wk = tid >> 4;         // 0..15
    const int wn4 = (tid & 15) * 4;  // 0..60
    float acc[4][4] = {};
    for (int k0 = 0; k0 < 2048; k0 += 32) {
        __syncthreads();
        float4 a0 = *(const float4*)(A + (size_t)(bm + arow) * 2048 + k0 + ak4);
        float4 a1 = *(const float4*)(A + (size_t)(bm + arow + 32) * 2048 + k0 + ak4);
        float4 w0 = *(const float4*)(W + (size_t)(k0 + wk) * 2048 + bn + wn4);
        float4 w1 = *(const float4*)(W + (size_t)(k0 + wk + 16) * 2048 + bn + wn4);
        As[ak4 + 0][arow] = a0.x; As[ak4 + 1][arow] = a0.y;
        As[ak4 + 2][arow] = a0.z; As[ak4 + 3][arow] = a0.w;
        As[ak4 + 0][arow + 32] = a1.x; As[ak4 + 1][arow + 32] = a1.y;
        As[ak4 + 2][arow + 32] = a1.z; As[ak4 + 3][arow + 32] = a1.w;
        *(float4*)&Bs[wk][wn4] = w0;
        *(float4*)&Bs[wk + 16][wn4] = w1;
        __syncthreads();
#pragma unroll
        for (int k = 0; k < 32; ++k) {
            float4 a = *(const float4*)&As[k][r0];
            float4 b = *(const float4*)&Bs[k][c0];
            acc[0][0] += a.x * b.x; acc[0][1] += a.x * b.y; acc[0][2] += a.x * b.z; acc[0][3] += a.x * b.w;
            acc[1][0] += a.y * b.x; acc[1][1] += a.y * b.y; acc[1][2] += a.y * b.z; acc[1][3] += a.y * b.w;
            acc[2][0] += a.z * b.x; acc[2][1] += a.z * b.y; acc[2][2] += a.z * b.z; acc[2][3] += a.z * b.w;
            acc[3][0] += a.w * b.x; acc[3][1] += a.w * b.y; acc[3][2] += a.w * b.z; acc[3][3] += a.w * b.w;
        }
    }
    if (!headmode) {
#pragma unroll
        for (int i = 0; i < 4; ++i) {
            float4 v = make_float4(acc[i][0], acc[i][1], acc[i][2], acc[i][3]);
            *(float4*)(C + (size_t)(bm + r0 + i) * 2048 + bn + c0) = v;
        }
    } else {
        int n0 = bn + c0;
        int h = n0 >> 7, d = n0 & 127;
#pragma unroll
        for (int i = 0; i < 4; ++i) {
            int m = bm + r0 + i;
            int b = m >> 10, s = m & 1023;
            float4 v = make_float4(acc[i][0], acc[i][1], acc[i][2], acc[i][3]);
            *(float4*)(C + ((size_t)((b << 4) | h) * 1024 + s) * 128 + d) = v;
        }
    }
}

// ---------------------------------------------------------------------------
// affinity: qa/ka [B,NH,S,NS]. One thread per (which, token, n).
// ---------------------------------------------------------------------------
__global__ __launch_bounds__(256) void affinity_kernel(
    const float* __restrict__ Q, const float* __restrict__ K,
    const float* __restrict__ posn, const float* __restrict__ dirn,
    const float* __restrict__ pos_sq, const float* __restrict__ pdv,
    const float* __restrict__ iv2s2, const float* __restrict__ ds_in,
    float* __restrict__ qa, float* __restrict__ ka) {
    int gid = blockIdx.x * 256 + threadIdx.x;  // 0 .. 2*32768*8-1
    int n = gid & 7;
    int t = (gid >> 3) & 32767;  // bh*1024 + s
    int which = gid >> 18;
    const float* T = (which ? K : Q) + (size_t)t * DD;
    int h = (t >> 10) & 15;
    const float* P = posn + (size_t)(h * 8 + n) * DD;
    const float* Dr = dirn + (size_t)(h * 8 + n) * DD;
    float tsq = 0.f, tp = 0.f, td = 0.f;
#pragma unroll 8
    for (int d = 0; d < DD; d += 4) {
        float4 tv = *(const float4*)(T + d);
        float4 pv = *(const float4*)(P + d);
        float4 dv = *(const float4*)(Dr + d);
        tsq += tv.x * tv.x + tv.y * tv.y + tv.z * tv.z + tv.w * tv.w;
        tp += tv.x * pv.x + tv.y * pv.y + tv.z * pv.z + tv.w * pv.w;
        td += tv.x * dv.x + tv.y * dv.y + tv.z * dv.z + tv.w * dv.w;
    }
    float dist2 = fmaxf(tsq - 2.f * tp + pos_sq[h * 8 + n], 0.f);
    float proj = td - pdv[h * 8 + n];
    float perp2 = fmaxf(dist2 - proj * proj, 0.f);
    float iv = iv2s2[h * 8 + n];
    float dsv = 1.f / (1.f + __expf(-ds_in[0]));
    float aff = (1.f - dsv) * __expf(-dist2 * iv) + dsv * __expf(-perp2 * iv);
    (which ? ka : qa)[(size_t)t * 8 + n] = aff;
}

// ---------------------------------------------------------------------------
// kv_s1: KV[bh,n,d] = sum_s ka[bh,s,n]*V[bh,s,d];  S1[bh,n] = sum_s ka[bh,s,n]
// One block (128 threads) per bh.
// ---------------------------------------------------------------------------
__global__ __launch_bounds__(128) void kv_s1_kernel(const float* __restrict__ ka,
                                                    const float* __restrict__ V,
                                                    float* __restrict__ KVv,
                                                    float* __restrict__ S1v) {
    int bh = blockIdx.x;
    int d = threadIdx.x;  // 0..127
    const float* kaB = ka + (size_t)bh * SD * 8;
    const float* VB = V + (size_t)bh * SD * DD;
    float acc[8] = {0, 0, 0, 0, 0, 0, 0, 0};
#pragma unroll 4
    for (int s = 0; s < SD; ++s) {
        float vd = VB[(size_t)s * DD + d];
        float4 k0 = *(const float4*)(kaB + (size_t)s * 8);
        float4 k1 = *(const float4*)(kaB + (size_t)s * 8 + 4);
        acc[0] += k0.x * vd; acc[1] += k0.y * vd; acc[2] += k0.z * vd; acc[3] += k0.w * vd;
        acc[4] += k1.x * vd; acc[5] += k1.y * vd; acc[6] += k1.z * vd; acc[7] += k1.w * vd;
    }
#pragma unroll
    for (int n = 0; n < 8; ++n) KVv[((size_t)bh * 8 + n) * DD + d] = acc[n];
    // S1: thread tid handles splat n = tid>>4 over chunk (tid&15)
    __shared__ float s1p[128];
    {
        int n = d >> 4, chunk = d & 15;
        float p = 0.f;
        for (int s = chunk * 64; s < chunk * 64 + 64; ++s) p += kaB[(size_t)s * 8 + n];
        s1p[d] = p;
    }
    __syncthreads();
    if (d < 8) {
        float t = 0.f;
        for (int c = 0; c < 16; ++c) t += s1p[(d << 4) + c];
        S1v[bh * 8 + d] = t;
    }
}

// ---------------------------------------------------------------------------
// flash_blend: per (bh, 32-row Q tile): std attention (online softmax) + closed
// form dgsa, blended, written to [B,S,HID] layout for the final Wo GEMM.
// ---------------------------------------------------------------------------
__global__ __launch_bounds__(256) void flash_blend(
    const float* __restrict__ Q, const float* __restrict__ K, const float* __restrict__ V,
    const float* __restrict__ qa, const float* __restrict__ amp,
    const float* __restrict__ S1v, const float* __restrict__ KVv,
    const float* __restrict__ gstr, float* __restrict__ blended) {
    __shared__ float Qs[32][132];
    __shared__ float Ks[32][132];
    __shared__ float Vs[32][132];
    __shared__ float Ps[32][36];
    const int bh = blockIdx.y;
    const int qt = blockIdx.x;
    const int tid = threadIdx.x;
    const int r = tid >> 3;  // 0..31 (row of tile)
    const int cg = tid & 7;  // col group
    const float qscale = 0.08838834764831845f;  // 1/sqrt(128)
    const float* Qbase = Q + (size_t)(bh * SD + qt * 32) * DD;
    const float* Kbase = K + (size_t)bh * SD * DD;
    const float* Vbase = V + (size_t)bh * SD * DD;
#pragma unroll
    for (int i = 0; i < 4; ++i) {
        int idx = tid + i * 256;  // 1024 float4s
        int row = idx >> 5;
        int c4 = (idx & 31) * 4;
        float4 v = *(const float4*)(Qbase + (size_t)row * DD + c4);
        v.x *= qscale; v.y *= qscale; v.z *= qscale; v.w *= qscale;
        *(float4*)&Qs[row][c4] = v;
    }
    float m_i = -INFINITY, l_i = 0.f;
    float o[16];
#pragma unroll
    for (int j = 0; j < 16; ++j) o[j] = 0.f;
    for (int kt = 0; kt < 32; ++kt) {
        __syncthreads();
#pragma unroll
        for (int i = 0; i < 4; ++i) {
            int idx = tid + i * 256;
            int row = idx >> 5;
            int c4 = (idx & 31) * 4;
            *(float4*)&Ks[row][c4] = *(const float4*)(Kbase + (size_t)(kt * 32 + row) * DD + c4);
            *(float4*)&Vs[row][c4] = *(const float4*)(Vbase + (size_t)(kt * 32 + row) * DD + c4);
        }
        __syncthreads();
        float sc0 = 0.f, sc1 = 0.f, sc2 = 0.f, sc3 = 0.f;
        const int c4 = cg * 4;
#pragma unroll 8
        for (int kk = 0; kk < DD; kk += 4) {
            float4 qv = *(const float4*)&Qs[r][kk];
            float4 k0 = *(const float4*)&Ks[c4 + 0][kk];
            float4 k1 = *(const float4*)&Ks[c4 + 1][kk];
            float4 k2 = *(const float4*)&Ks[c4 + 2][kk];
            float4 k3 = *(const float4*)&Ks[c4 + 3][kk];
            sc0 += qv.x * k0.x + qv.y * k0.y + qv.z * k0.z + qv.w * k0.w;
            sc1 += qv.x * k1.x + qv.y * k1.y + qv.z * k1.z + qv.w * k1.w;
            sc2 += qv.x * k2.x + qv.y * k2.y + qv.z * k2.z + qv.w * k2.w;
            sc3 += qv.x * k3.x + qv.y * k3.y + qv.z * k3.z + qv.w * k3.w;
        }
        float mx = fmaxf(fmaxf(sc0, sc1), fmaxf(sc2, sc3));
        mx = fmaxf(mx, __shfl_xor(mx, 1));
        mx = fmaxf(mx, __shfl_xor(mx, 2));
        mx = fmaxf(mx, __shfl_xor(mx, 4));
        float mnew = fmaxf(m_i, mx);
        float corr = __expf(m_i - mnew);
        float p0 = __expf(sc0 - mnew), p1 = __expf(sc1 - mnew);
        float p2 = __expf(sc2 - mnew), p3 = __expf(sc3 - mnew);
        float rs = p0 + p1 + p2 + p3;
        rs += __shfl_xor(rs, 1);
        rs += __shfl_xor(rs, 2);
        rs += __shfl_xor(rs, 4);
        l_i = l_i * corr + rs;
        m_i = mnew;
#pragma unroll
        for (int j = 0; j < 16; ++j) o[j] *= corr;
        Ps[r][c4 + 0] = p0; Ps[r][c4 + 1] = p1; Ps[r][c4 + 2] = p2; Ps[r][c4 + 3] = p3;
        __syncthreads();
#pragma unroll 4
        for (int k = 0; k < 32; ++k) {
            float pk = Ps[r][k];
            const float* vr = &Vs[k][cg * 16];
#pragma unroll
            for (int j4 = 0; j4 < 4; ++j4) {
                float4 vv = *(const float4*)(vr + j4 * 4);
                o[j4 * 4 + 0] += pk * vv.x;
                o[j4 * 4 + 1] += pk * vv.y;
                o[j4 * 4 + 2] += pk * vv.z;
                o[j4 * 4 + 3] += pk * vv.w;
            }
        }
    }
    // epilogue: std/l + blend with dgsa, write to [B,S,HID]
    float invl = 1.f / l_i;
    float gsa = 1.f / (1.f + __expf(-gstr[0]));
    float blend = fminf(0.05f, gsa * 0.1f);
    int q = qt * 32 + r;
    int h = bh & 15, b = bh >> 4;
    const float* qaRow = qa + ((size_t)bh * SD + q) * 8;
    float qam[8];
    float Z = 0.f;
#pragma unroll
    for (int n = 0; n < 8; ++n) {
        qam[n] = qaRow[n] * amp[h * 8 + n];
        Z += qam[n] * S1v[bh * 8 + n];
    }
    float invZ = 1.f / (Z + 1e-8f);
    float* outp = blended + (size_t)(b * SD + q) * HIDD + h * DD + cg * 16;
#pragma unroll
    for (int j4 = 0; j4 < 4; ++j4) {
        float dg0 = 0.f, dg1 = 0.f, dg2 = 0.f, dg3 = 0.f;
#pragma unroll
        for (int n = 0; n < 8; ++n) {
            const float* kvr = KVv + ((size_t)bh * 8 + n) * DD + cg * 16 + j4 * 4;
            dg0 += qam[n] * kvr[0];
            dg1 += qam[n] * kvr[1];
            dg2 += qam[n] * kvr[2];
            dg3 += qam[n] * kvr[3];
        }
        float4 v;
        v.x = (1.f - blend) * (o[j4 * 4 + 0] * invl) + blend * (dg0 * invZ);
        v.y = (1.f - blend) * (o[j4 * 4 + 1] * invl) + blend * (dg1 * invZ);
        v.z = (1.f - blend) * (o[j4 * 4 + 2] * invl) + blend * (dg2 * invZ);
        v.w = (1.f - blend) * (o[j4 * 4 + 3] * invl) + blend * (dg3 * invZ);
        *(float4*)(outp + j4 * 4) = v;
    }
}

// ---------------------------------------------------------------------------
extern "C" void kernel_launch(void* const* d_in, const int* in_sizes, int n_in,
                              void* d_out, int out_size, void* d_ws, size_t ws_size,
                              hipStream_t stream) {
    const float* X = (const float*)d_in[0];
    const float* Wq = (const float*)d_in[1];
    const float* Wk = (const float*)d_in[2];
    const float* Wv = (const float*)d_in[3];
    const float* Wo = (const float*)d_in[4];
    const float* sp = (const float*)d_in[5];
    const float* sd = (const float*)d_in[6];
    const float* ls = (const float*)d_in[7];
    const float* la = (const float*)d_in[8];
    const float* dstr = (const float*)d_in[9];
    const float* gstr = (const float*)d_in[10];

    float* ws = (float*)d_ws;
    float* Qw = ws;                    // [B,NH,S,D] 4194304
    float* Kw = Qw + 4194304;          // 4194304
    float* Vw = Kw + 4194304;          // 4194304
    float* qaw = Vw + 4194304;         // 262144
    float* kaw = qaw + 262144;         // 262144
    float* blended = kaw + 262144;     // [B,S,HID] 4194304
    float* posn = blended + 4194304;   // 16384
    float* dirn = posn + 16384;        // 16384
    float* pos_sq = dirn + 16384;      // 128
    float* pdv = pos_sq + 128;         // 128
    float* iv2s2 = pdv + 128;          // 128
    float* ampw = iv2s2 + 128;         // 128
    float* S1w = ampw + 128;           // 256
    float* KVw = S1w + 256;            // 32768

    splat_prep<<<1, 128, 0, stream>>>(sp, sd, ls, la, posn, dirn, pos_sq, pdv, iv2s2, ampw);
    gemm_tiled<<<dim3(32, 32), 256, 0, stream>>>(X, Wq, Qw, 1);
    gemm_tiled<<<dim3(32, 32), 256, 0, stream>>>(X, Wk, Kw, 1);
    gemm_tiled<<<dim3(32, 32), 256, 0, stream>>>(X, Wv, Vw, 1);
    affinity_kernel<<<2048, 256, 0, stream>>>(Qw, Kw, posn, dirn, pos_sq, pdv, iv2s2, dstr, qaw, kaw);
    kv_s1_kernel<<<32, 128, 0, stream>>>(kaw, Vw, KVw, S1w);
    flash_blend<<<dim3(32, 32), 256, 0, stream>>>(Qw, Kw, Vw, qaw, ampw, S1w, KVw, gstr, blended);
    gemm_tiled<<<dim3(32, 32), 256, 0, stream>>>(blended, Wo, (float*)d_out, 0);
}

// Round 2
// 606.973 us; speedup vs baseline: 2.9473x; 2.9473x over previous
//
#include <hip/hip_runtime.h>
#include <math.h>

typedef __attribute__((ext_vector_type(8))) short bf16x8;
typedef __attribute__((ext_vector_type(4))) float f32x4;

__device__ __forceinline__ unsigned short f2b(float f) {
    unsigned u = __float_as_uint(f);
    unsigned r = (u + 0x7fffu + ((u >> 16) & 1u)) >> 16;
    return (unsigned short)r;
}
__device__ __forceinline__ float b2f(unsigned short h) {
    return __uint_as_float(((unsigned)h) << 16);
}

__device__ __forceinline__ void async_copy16(const void* g, void* l) {
    __builtin_amdgcn_global_load_lds((const __attribute__((address_space(1))) void*)g,
                                     (__attribute__((address_space(3))) void*)l, 16, 0, 0);
}

// ---------------------------------------------------------------------------
// splat_prep (unchanged, fp32): normalize positions/directions, precompute.
// ---------------------------------------------------------------------------
__global__ void splat_prep(const float* __restrict__ sp, const float* __restrict__ sd,
                           const float* __restrict__ ls, const float* __restrict__ la,
                           float* __restrict__ posn, float* __restrict__ dirn,
                           float* __restrict__ pos_sq, float* __restrict__ pdv,
                           float* __restrict__ iv2s2, float* __restrict__ amp) {
    int i = threadIdx.x;  // 0..127
    const float* p = sp + (size_t)i * 128;
    const float* d = sd + (size_t)i * 128;
    float np_ = 0.f, nd_ = 0.f;
    for (int k = 0; k < 128; ++k) { np_ += p[k] * p[k]; nd_ += d[k] * d[k]; }
    np_ = sqrtf(np_); nd_ = sqrtf(nd_);
    const float sc = 3.394112549695428f;  // sqrt(128)*0.3
    float rp = sc / (np_ + 1e-12f);
    float rd = 1.f / (nd_ + 1e-12f);
    float psq = 0.f, pd_ = 0.f;
    for (int k = 0; k < 128; ++k) {
        float pn = p[k] * rp;
        float dn = d[k] * rd;
        posn[(size_t)i * 128 + k] = pn;
        dirn[(size_t)i * 128 + k] = dn;
        psq += pn * pn;
        pd_ += pn * dn;
    }
    pos_sq[i] = psq;
    pdv[i] = pd_;
    float s = expf(ls[i]);
    s = fminf(fmaxf(s, 0.3f), 1.2f);
    iv2s2[i] = 0.5f / (s * s);
    if ((i & 7) == 0) {
        int h = i >> 3;
        float mx = -INFINITY;
        for (int n = 0; n < 8; ++n) mx = fmaxf(mx, la[h * 8 + n]);
        float e[8]; float ssum = 0.f;
        for (int n = 0; n < 8; ++n) { e[n] = expf(la[h * 8 + n] - mx); ssum += e[n]; }
        for (int n = 0; n < 8; ++n) amp[h * 8 + n] = e[n] / ssum;
    }
}

// ---------------------------------------------------------------------------
// convert_x: fp32 [2048*2048] -> bf16 same layout.
// ---------------------------------------------------------------------------
__global__ __launch_bounds__(256) void convert_x(const float* __restrict__ X,
                                                 unsigned short* __restrict__ Y) {
    int i = (blockIdx.x * 256 + threadIdx.x) * 4;
    float4 v = *(const float4*)(X + i);
    ushort4 o;
    o.x = f2b(v.x); o.y = f2b(v.y); o.z = f2b(v.z); o.w = f2b(v.w);
    *(ushort4*)(Y + i) = o;
}

// ---------------------------------------------------------------------------
// transpose_w: WT[n][k] = bf16(W[k][n]), 2048x2048.
// ---------------------------------------------------------------------------
__global__ __launch_bounds__(256) void transpose_w(const float* __restrict__ W,
                                                   unsigned short* __restrict__ WT) {
    __shared__ float t[32][33];
    int tx = threadIdx.x & 31, ty = threadIdx.x >> 5;  // ty 0..7
    int bn = blockIdx.x * 32, bk = blockIdx.y * 32;
#pragma unroll
    for (int i = 0; i < 4; ++i)
        t[ty + i * 8][tx] = W[(size_t)(bk + ty + i * 8) * 2048 + bn + tx];
    __syncthreads();
#pragma unroll
    for (int i = 0; i < 4; ++i)
        WT[(size_t)(bn + ty + i * 8) * 2048 + bk + tx] = f2b(t[tx][ty + i * 8]);
}

// ---------------------------------------------------------------------------
// gemm_bf16: C = A(bf16 [2048][2048]) @ BT(bf16 [n][k])^T.  128x128 tile,
// BK=32, 4 waves each 64x64 via 4x4 grid of 16x16x32 MFMA (m97 structure).
// mode 0: fp32 row-major out. mode 1: bf16 head layout [b,h,s,d].
// mode 3: mode1 + transposed copy [b,h,d,s].
// ---------------------------------------------------------------------------
__global__ __launch_bounds__(256) void gemm_bf16(const unsigned short* __restrict__ A,
                                                 const unsigned short* __restrict__ BT,
                                                 float* __restrict__ Cf,
                                                 unsigned short* __restrict__ Cb,
                                                 unsigned short* __restrict__ Ct,
                                                 int mode) {
    __shared__ unsigned short As[128 * 32];
    __shared__ unsigned short Bs[128 * 32];
    const int tid = threadIdx.x;
    const int lane = tid & 63, wave = tid >> 6;
    const int l15 = lane & 15, quad = lane >> 4;
    const int wm = (wave >> 1) * 64, wn = (wave & 1) * 64;
    const int bm = blockIdx.x * 128, bn = blockIdx.y * 128;
    f32x4 acc[4][4] = {};
    const int off0 = tid * 16;       // byte offset in LDS, 0..4080
    const int row0 = off0 >> 6;      // tid/4
    const int ch0 = (off0 >> 4) & 3; // k-chunk
    const unsigned short* ga = A + (size_t)(bm + row0) * 2048 + ch0 * 8;
    const unsigned short* gb = BT + (size_t)(bn + row0) * 2048 + ch0 * 8;
    for (int k0 = 0; k0 < 2048; k0 += 32) {
        __syncthreads();
        async_copy16(ga + k0, (char*)As + off0);
        async_copy16(ga + (size_t)64 * 2048 + k0, (char*)As + off0 + 4096);
        async_copy16(gb + k0, (char*)Bs + off0);
        async_copy16(gb + (size_t)64 * 2048 + k0, (char*)Bs + off0 + 4096);
        __syncthreads();
        bf16x8 af[4], bf[4];
#pragma unroll
        for (int i = 0; i < 4; ++i)
            af[i] = *(const bf16x8*)((const char*)As + ((wm + i * 16 + l15) * 32 + quad * 8) * 2);
#pragma unroll
        for (int j = 0; j < 4; ++j)
            bf[j] = *(const bf16x8*)((const char*)Bs + ((wn + j * 16 + l15) * 32 + quad * 8) * 2);
#pragma unroll
        for (int i = 0; i < 4; ++i)
#pragma unroll
            for (int j = 0; j < 4; ++j)
                acc[i][j] = __builtin_amdgcn_mfma_f32_16x16x32_bf16(af[i], bf[j], acc[i][j], 0, 0, 0);
    }
#pragma unroll
    for (int i = 0; i < 4; ++i) {
#pragma unroll
        for (int j = 0; j < 4; ++j) {
#pragma unroll
            for (int r = 0; r < 4; ++r) {
                int m = bm + wm + i * 16 + quad * 4 + r;
                int n = bn + wn + j * 16 + l15;
                float v = acc[i][j][r];
                if (mode == 0) {
                    Cf[(size_t)m * 2048 + n] = v;
                } else {
                    int b = m >> 10, s = m & 1023, h = n >> 7, d = n & 127;
                    unsigned short bv = f2b(v);
                    Cb[((size_t)((b << 4) | h) * 1024 + s) * 128 + d] = bv;
                    if (mode == 3) Ct[((size_t)((b << 4) | h) * 128 + d) * 1024 + s] = bv;
                }
            }
        }
    }
}

// ---------------------------------------------------------------------------
// affinity: qa/ka [B,NH,S,NS] fp32 from bf16 Q/K head layout.
// ---------------------------------------------------------------------------
__global__ __launch_bounds__(256) void affinity_kernel(
    const unsigned short* __restrict__ Q, const unsigned short* __restrict__ K,
    const float* __restrict__ posn, const float* __restrict__ dirn,
    const float* __restrict__ pos_sq, const float* __restrict__ pdv,
    const float* __restrict__ iv2s2, const float* __restrict__ ds_in,
    float* __restrict__ qa, float* __restrict__ ka) {
    int gid = blockIdx.x * 256 + threadIdx.x;
    int n = gid & 7;
    int t = (gid >> 3) & 32767;
    int which = gid >> 18;
    const unsigned short* T = (which ? K : Q) + (size_t)t * 128;
    int h = (t >> 10) & 15;
    const float* P = posn + (size_t)(h * 8 + n) * 128;
    const float* Dr = dirn + (size_t)(h * 8 + n) * 128;
    float tsq = 0.f, tp = 0.f, td = 0.f;
#pragma unroll
    for (int d = 0; d < 128; d += 8) {
        uint4 raw = *(const uint4*)(T + d);
        float tv[8];
        tv[0] = __uint_as_float(raw.x << 16); tv[1] = __uint_as_float(raw.x & 0xffff0000u);
        tv[2] = __uint_as_float(raw.y << 16); tv[3] = __uint_as_float(raw.y & 0xffff0000u);
        tv[4] = __uint_as_float(raw.z << 16); tv[5] = __uint_as_float(raw.z & 0xffff0000u);
        tv[6] = __uint_as_float(raw.w << 16); tv[7] = __uint_as_float(raw.w & 0xffff0000u);
        float4 p0 = *(const float4*)(P + d), p1 = *(const float4*)(P + d + 4);
        float4 d0 = *(const float4*)(Dr + d), d1 = *(const float4*)(Dr + d + 4);
        tsq += tv[0]*tv[0]+tv[1]*tv[1]+tv[2]*tv[2]+tv[3]*tv[3]+tv[4]*tv[4]+tv[5]*tv[5]+tv[6]*tv[6]+tv[7]*tv[7];
        tp  += tv[0]*p0.x+tv[1]*p0.y+tv[2]*p0.z+tv[3]*p0.w+tv[4]*p1.x+tv[5]*p1.y+tv[6]*p1.z+tv[7]*p1.w;
        td  += tv[0]*d0.x+tv[1]*d0.y+tv[2]*d0.z+tv[3]*d0.w+tv[4]*d1.x+tv[5]*d1.y+tv[6]*d1.z+tv[7]*d1.w;
    }
    float dist2 = fmaxf(tsq - 2.f * tp + pos_sq[h * 8 + n], 0.f);
    float proj = td - pdv[h * 8 + n];
    float perp2 = fmaxf(dist2 - proj * proj, 0.f);
    float iv = iv2s2[h * 8 + n];
    float dsv = 1.f / (1.f + __expf(-ds_in[0]));
    float aff = (1.f - dsv) * __expf(-dist2 * iv) + dsv * __expf(-perp2 * iv);
    (which ? ka : qa)[(size_t)t * 8 + n] = aff;
}

// ---------------------------------------------------------------------------
// kv_s1: KV[bh,n,d] = sum_s ka[bh,s,n]*V[bh,s,d];  S1[bh,n] = sum_s ka[bh,s,n]
// ---------------------------------------------------------------------------
__global__ __launch_bounds__(128) void kv_s1_kernel(const float* __restrict__ ka,
                                                    const unsigned short* __restrict__ V,
                                                    float* __restrict__ KVv,
                                                    float* __restrict__ S1v) {
    int bh = blockIdx.x;
    int d = threadIdx.x;
    const float* kaB = ka + (size_t)bh * 1024 * 8;
    const unsigned short* VB = V + (size_t)bh * 1024 * 128;
    float acc[8] = {};
#pragma unroll 4
    for (int s = 0; s < 1024; ++s) {
        float vd = b2f(VB[(size_t)s * 128 + d]);
        float4 k0 = *(const float4*)(kaB + (size_t)s * 8);
        float4 k1 = *(const float4*)(kaB + (size_t)s * 8 + 4);
        acc[0] += k0.x * vd; acc[1] += k0.y * vd; acc[2] += k0.z * vd; acc[3] += k0.w * vd;
        acc[4] += k1.x * vd; acc[5] += k1.y * vd; acc[6] += k1.z * vd; acc[7] += k1.w * vd;
    }
#pragma unroll
    for (int n = 0; n < 8; ++n) KVv[((size_t)bh * 8 + n) * 128 + d] = acc[n];
    __shared__ float s1p[128];
    {
        int n = d >> 4, chunk = d & 15;
        float p = 0.f;
        for (int s = chunk * 64; s < chunk * 64 + 64; ++s) p += kaB[(size_t)s * 8 + n];
        s1p[d] = p;
    }
    __syncthreads();
    if (d < 8) {
        float t = 0.f;
        for (int c = 0; c < 16; ++c) t += s1p[(d << 4) + c];
        S1v[bh * 8 + d] = t;
    }
}

// ---------------------------------------------------------------------------
// flash_blend (MFMA): per (bh, 64-row Q tile). 4 waves, each owns 16 Q rows.
// QK^T and PV on mfma_f32_16x16x32_bf16; online softmax on C-layout frags;
// P goes through padded LDS (C-layout -> A-layout). Blended with closed-form
// dgsa and written bf16 to [B,S,HID].
// ---------------------------------------------------------------------------
__global__ __launch_bounds__(256) void flash_blend(
    const unsigned short* __restrict__ Qg, const unsigned short* __restrict__ Kg,
    const unsigned short* __restrict__ Vtg,
    const float* __restrict__ qa, const float* __restrict__ amp,
    const float* __restrict__ S1v, const float* __restrict__ KVv,
    const float* __restrict__ gstr, unsigned short* __restrict__ blended) {
    __shared__ unsigned short Qs[64 * 128];   // [qrow][d]
    __shared__ unsigned short Ks[32 * 128];   // [key][d]
    __shared__ unsigned short Vt[128 * 32];   // [d][key]
    __shared__ unsigned short Ps[4][16 * 40]; // per wave, [m][k] stride 40
    __shared__ float KVs[8 * 128];
    const int tid = threadIdx.x, lane = tid & 63, wave = tid >> 6;
    const int l15 = lane & 15, quad = lane >> 4;
    const int bh = blockIdx.y, qt = blockIdx.x;
    const float qscale = 0.08838834764831845f;  // 1/sqrt(128)

    const unsigned short* Qbase = Qg + ((size_t)bh * 1024 + qt * 64) * 128;
    const unsigned short* Kbase = Kg + (size_t)bh * 1024 * 128;
    const unsigned short* Vbase = Vtg + (size_t)bh * 128 * 1024;
#pragma unroll
    for (int i = 0; i < 4; ++i)
        async_copy16((const char*)Qbase + tid * 16 + i * 4096, (char*)Qs + tid * 16 + i * 4096);
    *(f32x4*)(KVs + tid * 4) = *(const f32x4*)(KVv + (size_t)bh * 1024 + tid * 4);

    f32x4 o[8] = {};
    float m_i[4] = {-INFINITY, -INFINITY, -INFINITY, -INFINITY};
    float l_i[4] = {};

    for (int kt = 0; kt < 32; ++kt) {
        __syncthreads();
#pragma unroll
        for (int i = 0; i < 2; ++i) {
            int off = tid * 16 + i * 4096;
            async_copy16((const char*)Kbase + (size_t)kt * 8192 + off, (char*)Ks + off);
            int drow = off >> 6, ch = (off >> 4) & 3;
            async_copy16(Vbase + (size_t)drow * 1024 + kt * 32 + ch * 8, (char*)Vt + off);
        }
        __syncthreads();
        // QK^T: 16 q-rows x 32 keys per wave
        f32x4 sc[2] = {};
#pragma unroll
        for (int k4 = 0; k4 < 4; ++k4) {
            bf16x8 aq = *(const bf16x8*)((const char*)Qs + ((wave * 16 + l15) * 128 + k4 * 32 + quad * 8) * 2);
            bf16x8 b0 = *(const bf16x8*)((const char*)Ks + ((l15) * 128 + k4 * 32 + quad * 8) * 2);
            bf16x8 b1 = *(const bf16x8*)((const char*)Ks + ((16 + l15) * 128 + k4 * 32 + quad * 8) * 2);
            sc[0] = __builtin_amdgcn_mfma_f32_16x16x32_bf16(aq, b0, sc[0], 0, 0, 0);
            sc[1] = __builtin_amdgcn_mfma_f32_16x16x32_bf16(aq, b1, sc[1], 0, 0, 0);
        }
        // online softmax per row (row = quad*4+r, cols across 16 lanes of quad)
        float pv0[4], pv1[4], corr[4];
#pragma unroll
        for (int r = 0; r < 4; ++r) {
            float s0 = sc[0][r] * qscale, s1 = sc[1][r] * qscale;
            float mx = fmaxf(s0, s1);
            mx = fmaxf(mx, __shfl_xor(mx, 1));
            mx = fmaxf(mx, __shfl_xor(mx, 2));
            mx = fmaxf(mx, __shfl_xor(mx, 4));
            mx = fmaxf(mx, __shfl_xor(mx, 8));
            float mn = fmaxf(m_i[r], mx);
            float c = __expf(m_i[r] - mn);
            float p0 = __expf(s0 - mn), p1 = __expf(s1 - mn);
            float rs = p0 + p1;
            rs += __shfl_xor(rs, 1);
            rs += __shfl_xor(rs, 2);
            rs += __shfl_xor(rs, 4);
            rs += __shfl_xor(rs, 8);
            l_i[r] = l_i[r] * c + rs;
            m_i[r] = mn;
            corr[r] = c;
            pv0[r] = p0; pv1[r] = p1;
        }
#pragma unroll
        for (int j = 0; j < 8; ++j) {
            o[j][0] *= corr[0]; o[j][1] *= corr[1];
            o[j][2] *= corr[2]; o[j][3] *= corr[3];
        }
        unsigned short* Pw = &Ps[wave][0];
#pragma unroll
        for (int r = 0; r < 4; ++r) {
            Pw[(quad * 4 + r) * 40 + l15] = f2b(pv0[r]);
            Pw[(quad * 4 + r) * 40 + 16 + l15] = f2b(pv1[r]);
        }
        __syncthreads();
        // PV: P (16x32) @ V (32x128)
        bf16x8 ap = *(const bf16x8*)((const char*)Pw + (l15 * 40 + quad * 8) * 2);
#pragma unroll
        for (int j = 0; j < 8; ++j) {
            bf16x8 bv = *(const bf16x8*)((const char*)Vt + ((j * 16 + l15) * 32 + quad * 8) * 2);
            o[j] = __builtin_amdgcn_mfma_f32_16x16x32_bf16(ap, bv, o[j], 0, 0, 0);
        }
    }
    // epilogue
    float gsa = 1.f / (1.f + __expf(-gstr[0]));
    float blend = fminf(0.05f, gsa * 0.1f);
    int b = bh >> 4, h = bh & 15;
#pragma unroll
    for (int r = 0; r < 4; ++r) {
        int q = qt * 64 + wave * 16 + quad * 4 + r;
        const float* qaRow = qa + ((size_t)bh * 1024 + q) * 8;
        float qam[8], Z = 0.f;
#pragma unroll
        for (int n = 0; n < 8; ++n) {
            qam[n] = qaRow[n] * amp[h * 8 + n];
            Z += qam[n] * S1v[bh * 8 + n];
        }
        float invZ = 1.f / (Z + 1e-8f);
        float invl = 1.f / l_i[r];
        unsigned short* outp = blended + ((size_t)(b * 1024 + q)) * 2048 + h * 128;
#pragma unroll
        for (int j = 0; j < 8; ++j) {
            int d = j * 16 + l15;
            float dg = 0.f;
#pragma unroll
            for (int n = 0; n < 8; ++n) dg += qam[n] * KVs[n * 128 + d];
            float v = (1.f - blend) * (o[j][r] * invl) + blend * (dg * invZ);
            outp[d] = f2b(v);
        }
    }
}

// ---------------------------------------------------------------------------
extern "C" void kernel_launch(void* const* d_in, const int* in_sizes, int n_in,
                              void* d_out, int out_size, void* d_ws, size_t ws_size,
                              hipStream_t stream) {
    const float* X = (const float*)d_in[0];
    const float* Wq = (const float*)d_in[1];
    const float* Wk = (const float*)d_in[2];
    const float* Wv = (const float*)d_in[3];
    const float* Wo = (const float*)d_in[4];
    const float* sp = (const float*)d_in[5];
    const float* sd = (const float*)d_in[6];
    const float* ls = (const float*)d_in[7];
    const float* la = (const float*)d_in[8];
    const float* dstr = (const float*)d_in[9];
    const float* gstr = (const float*)d_in[10];

    char* base = (char*)d_ws;
    unsigned short* WT = (unsigned short*)base;            base += 8388608;
    unsigned short* Xbf = (unsigned short*)base;           base += 8388608;
    unsigned short* Qbf = (unsigned short*)base;           base += 8388608;
    unsigned short* Kbf = (unsigned short*)base;           base += 8388608;
    unsigned short* Vbf = (unsigned short*)base;           base += 8388608;
    unsigned short* Vtb = (unsigned short*)base;           base += 8388608;
    unsigned short* blended = (unsigned short*)base;       base += 8388608;
    float* qaw = (float*)base;                             base += 1048576;
    float* kaw = (float*)base;                             base += 1048576;
    float* posn = (float*)base;                            base += 65536;
    float* dirn = (float*)base;                            base += 65536;
    float* pos_sq = (float*)base;                          base += 512;
    float* pdv = (float*)base;                             base += 512;
    float* iv2s2 = (float*)base;                           base += 512;
    float* ampw = (float*)base;                            base += 512;
    float* S1w = (float*)base;                             base += 1024;
    float* KVw = (float*)base;                             base += 131072;

    splat_prep<<<1, 128, 0, stream>>>(sp, sd, ls, la, posn, dirn, pos_sq, pdv, iv2s2, ampw);
    convert_x<<<4096, 256, 0, stream>>>(X, Xbf);

    transpose_w<<<dim3(64, 64), 256, 0, stream>>>(Wq, WT);
    gemm_bf16<<<dim3(16, 16), 256, 0, stream>>>(Xbf, WT, nullptr, Qbf, nullptr, 1);
    transpose_w<<<dim3(64, 64), 256, 0, stream>>>(Wk, WT);
    gemm_bf16<<<dim3(16, 16), 256, 0, stream>>>(Xbf, WT, nullptr, Kbf, nullptr, 1);
    transpose_w<<<dim3(64, 64), 256, 0, stream>>>(Wv, WT);
    gemm_bf16<<<dim3(16, 16), 256, 0, stream>>>(Xbf, WT, nullptr, Vbf, Vtb, 3);

    affinity_kernel<<<2048, 256, 0, stream>>>(Qbf, Kbf, posn, dirn, pos_sq, pdv, iv2s2, dstr, qaw, kaw);
    kv_s1_kernel<<<32, 128, 0, stream>>>(kaw, Vbf, KVw, S1w);

    transpose_w<<<dim3(64, 64), 256, 0, stream>>>(Wo, WT);
    flash_blend<<<dim3(16, 32), 256, 0, stream>>>(Qbf, Kbf, Vtb, qaw, ampw, S1w, KVw, gstr, blended);
    gemm_bf16<<<dim3(16, 16), 256, 0, stream>>>(blended, WT, (float*)d_out, nullptr, nullptr, 0);
}

// Round 3
// 408.255 us; speedup vs baseline: 4.3818x; 1.4868x over previous
//
#include <hip/hip_runtime.h>
#include <math.h>

typedef __attribute__((ext_vector_type(8))) short bf16x8;
typedef __attribute__((ext_vector_type(4))) float f32x4;
typedef unsigned short ushort_t;

__device__ __forceinline__ unsigned short f2b(float f) {
    unsigned u = __float_as_uint(f);
    unsigned r = (u + 0x7fffu + ((u >> 16) & 1u)) >> 16;
    return (unsigned short)r;
}
__device__ __forceinline__ float b2f(unsigned short h) {
    return __uint_as_float(((unsigned)h) << 16);
}

__device__ __forceinline__ void async_copy16(const void* g, void* l) {
    __builtin_amdgcn_global_load_lds((const __attribute__((address_space(1))) void*)g,
                                     (__attribute__((address_space(3))) void*)l, 16, 0, 0);
}

// ---------------------------------------------------------------------------
// splat_prep: normalize positions/directions, precompute constants.
// ---------------------------------------------------------------------------
__global__ void splat_prep(const float* __restrict__ sp, const float* __restrict__ sd,
                           const float* __restrict__ ls, const float* __restrict__ la,
                           float* __restrict__ posn, float* __restrict__ dirn,
                           float* __restrict__ pos_sq, float* __restrict__ pdv,
                           float* __restrict__ iv2s2, float* __restrict__ amp) {
    int i = threadIdx.x;  // 0..127
    const float* p = sp + (size_t)i * 128;
    const float* d = sd + (size_t)i * 128;
    float np_ = 0.f, nd_ = 0.f;
    for (int k = 0; k < 128; ++k) { np_ += p[k] * p[k]; nd_ += d[k] * d[k]; }
    np_ = sqrtf(np_); nd_ = sqrtf(nd_);
    const float sc = 3.394112549695428f;  // sqrt(128)*0.3
    float rp = sc / (np_ + 1e-12f);
    float rd = 1.f / (nd_ + 1e-12f);
    float psq = 0.f, pd_ = 0.f;
    for (int k = 0; k < 128; ++k) {
        float pn = p[k] * rp;
        float dn = d[k] * rd;
        posn[(size_t)i * 128 + k] = pn;
        dirn[(size_t)i * 128 + k] = dn;
        psq += pn * pn;
        pd_ += pn * dn;
    }
    pos_sq[i] = psq;
    pdv[i] = pd_;
    float s = expf(ls[i]);
    s = fminf(fmaxf(s, 0.3f), 1.2f);
    iv2s2[i] = 0.5f / (s * s);
    if ((i & 7) == 0) {
        int h = i >> 3;
        float mx = -INFINITY;
        for (int n = 0; n < 8; ++n) mx = fmaxf(mx, la[h * 8 + n]);
        float e[8]; float ssum = 0.f;
        for (int n = 0; n < 8; ++n) { e[n] = expf(la[h * 8 + n] - mx); ssum += e[n]; }
        for (int n = 0; n < 8; ++n) amp[h * 8 + n] = e[n] / ssum;
    }
}

// ---------------------------------------------------------------------------
// convert_x: fp32 [2048*2048] -> bf16.
// ---------------------------------------------------------------------------
__global__ __launch_bounds__(256) void convert_x(const float* __restrict__ X,
                                                 ushort_t* __restrict__ Y) {
    int i = (blockIdx.x * 256 + threadIdx.x) * 4;
    float4 v = *(const float4*)(X + i);
    ushort4 o;
    o.x = f2b(v.x); o.y = f2b(v.y); o.z = f2b(v.z); o.w = f2b(v.w);
    *(ushort4*)(Y + i) = o;
}

// ---------------------------------------------------------------------------
// transpose_w: WT[n][k] = bf16(W[k][n]), 2048x2048.
// ---------------------------------------------------------------------------
__global__ __launch_bounds__(256) void transpose_w(const float* __restrict__ W,
                                                   ushort_t* __restrict__ WT) {
    __shared__ float t[32][33];
    int tx = threadIdx.x & 31, ty = threadIdx.x >> 5;
    int bn = blockIdx.x * 32, bk = blockIdx.y * 32;
#pragma unroll
    for (int i = 0; i < 4; ++i)
        t[ty + i * 8][tx] = W[(size_t)(bk + ty + i * 8) * 2048 + bn + tx];
    __syncthreads();
#pragma unroll
    for (int i = 0; i < 4; ++i)
        WT[(size_t)(bn + ty + i * 8) * 2048 + bk + tx] = f2b(t[tx][ty + i * 8]);
}

// ---------------------------------------------------------------------------
// gemm_qkv: fused Q/K/V projection. grid (16, 48); blockIdx.y>>4 selects the
// weight matrix (WT3 = [Wq^T;Wk^T;Wv^T] bf16). 128x128 tile, BK=32, m97 form.
// Q/K/V written to bf16 head layout [b,h,s,d]; V additionally [b,h,d,s].
// ---------------------------------------------------------------------------
__global__ __launch_bounds__(256) void gemm_qkv(const ushort_t* __restrict__ A,
                                                const ushort_t* __restrict__ WT3,
                                                ushort_t* __restrict__ Qb,
                                                ushort_t* __restrict__ Kb,
                                                ushort_t* __restrict__ Vb,
                                                ushort_t* __restrict__ Vt) {
    __shared__ ushort_t As[128 * 32];
    __shared__ ushort_t Bs[128 * 32];
    const int tid = threadIdx.x, lane = tid & 63, wave = tid >> 6;
    const int l15 = lane & 15, quad = lane >> 4;
    const int wm = (wave >> 1) * 64, wn = (wave & 1) * 64;
    const int bm = blockIdx.x * 128;
    const int by = blockIdx.y, which = by >> 4, bn = (by & 15) * 128;
    const ushort_t* BT = WT3 + (size_t)which * 4194304;
    f32x4 acc[4][4] = {};
    const int off0 = tid * 16, row0 = off0 >> 6, ch0 = (off0 >> 4) & 3;
    const ushort_t* ga = A + (size_t)(bm + row0) * 2048 + ch0 * 8;
    const ushort_t* gb = BT + (size_t)(bn + row0) * 2048 + ch0 * 8;
    for (int k0 = 0; k0 < 2048; k0 += 32) {
        __syncthreads();
        async_copy16(ga + k0, (char*)As + off0);
        async_copy16(ga + (size_t)64 * 2048 + k0, (char*)As + off0 + 4096);
        async_copy16(gb + k0, (char*)Bs + off0);
        async_copy16(gb + (size_t)64 * 2048 + k0, (char*)Bs + off0 + 4096);
        __syncthreads();
        bf16x8 af[4], bfr[4];
#pragma unroll
        for (int i = 0; i < 4; ++i)
            af[i] = *(const bf16x8*)((const char*)As + ((wm + i * 16 + l15) * 32 + quad * 8) * 2);
#pragma unroll
        for (int j = 0; j < 4; ++j)
            bfr[j] = *(const bf16x8*)((const char*)Bs + ((wn + j * 16 + l15) * 32 + quad * 8) * 2);
#pragma unroll
        for (int i = 0; i < 4; ++i)
#pragma unroll
            for (int j = 0; j < 4; ++j)
                acc[i][j] = __builtin_amdgcn_mfma_f32_16x16x32_bf16(af[i], bfr[j], acc[i][j], 0, 0, 0);
    }
    ushort_t* Cb = (which == 0) ? Qb : ((which == 1) ? Kb : Vb);
    const bool dot = (which == 2);
#pragma unroll
    for (int i = 0; i < 4; ++i) {
#pragma unroll
        for (int j = 0; j < 4; ++j) {
#pragma unroll
            for (int r = 0; r < 4; ++r) {
                int m = bm + wm + i * 16 + quad * 4 + r;
                int n = bn + wn + j * 16 + l15;
                int b = m >> 10, s = m & 1023, h = n >> 7, d = n & 127;
                unsigned short bv = f2b(acc[i][j][r]);
                Cb[((size_t)((b << 4) | h) * 1024 + s) * 128 + d] = bv;
                if (dot) Vt[((size_t)((b << 4) | h) * 128 + d) * 1024 + s] = bv;
            }
        }
    }
}

// ---------------------------------------------------------------------------
// gemm_out: C(fp32) = A(bf16) @ BT^T. 128x64 tile -> grid (16,32) = 512 blocks.
// ---------------------------------------------------------------------------
__global__ __launch_bounds__(256) void gemm_out(const ushort_t* __restrict__ A,
                                                const ushort_t* __restrict__ BT,
                                                float* __restrict__ Cf) {
    __shared__ ushort_t As[128 * 32];
    __shared__ ushort_t Bs[64 * 32];
    const int tid = threadIdx.x, lane = tid & 63, wave = tid >> 6;
    const int l15 = lane & 15, quad = lane >> 4;
    const int wm = (wave >> 1) * 64, wn = (wave & 1) * 32;
    const int bm = blockIdx.x * 128, bn = blockIdx.y * 64;
    f32x4 acc[4][2] = {};
    const int off0 = tid * 16, row0 = off0 >> 6, ch0 = (off0 >> 4) & 3;
    const ushort_t* ga = A + (size_t)(bm + row0) * 2048 + ch0 * 8;
    const ushort_t* gb = BT + (size_t)(bn + row0) * 2048 + ch0 * 8;
    for (int k0 = 0; k0 < 2048; k0 += 32) {
        __syncthreads();
        async_copy16(ga + k0, (char*)As + off0);
        async_copy16(ga + (size_t)64 * 2048 + k0, (char*)As + off0 + 4096);
        async_copy16(gb + k0, (char*)Bs + off0);
        __syncthreads();
        bf16x8 af[4], bfr[2];
#pragma unroll
        for (int i = 0; i < 4; ++i)
            af[i] = *(const bf16x8*)((const char*)As + ((wm + i * 16 + l15) * 32 + quad * 8) * 2);
#pragma unroll
        for (int j = 0; j < 2; ++j)
            bfr[j] = *(const bf16x8*)((const char*)Bs + ((wn + j * 16 + l15) * 32 + quad * 8) * 2);
#pragma unroll
        for (int i = 0; i < 4; ++i)
#pragma unroll
            for (int j = 0; j < 2; ++j)
                acc[i][j] = __builtin_amdgcn_mfma_f32_16x16x32_bf16(af[i], bfr[j], acc[i][j], 0, 0, 0);
    }
#pragma unroll
    for (int i = 0; i < 4; ++i)
#pragma unroll
        for (int j = 0; j < 2; ++j)
#pragma unroll
            for (int r = 0; r < 4; ++r) {
                int m = bm + wm + i * 16 + quad * 4 + r;
                int n = bn + wn + j * 16 + l15;
                Cf[(size_t)m * 2048 + n] = acc[i][j][r];
            }
}

// ---------------------------------------------------------------------------
// affinity: qa/ka [B,NH,S,NS] fp32 from bf16 Q/K head layout.
// ---------------------------------------------------------------------------
__global__ __launch_bounds__(256) void affinity_kernel(
    const ushort_t* __restrict__ Q, const ushort_t* __restrict__ K,
    const float* __restrict__ posn, const float* __restrict__ dirn,
    const float* __restrict__ pos_sq, const float* __restrict__ pdv,
    const float* __restrict__ iv2s2, const float* __restrict__ ds_in,
    float* __restrict__ qa, float* __restrict__ ka) {
    int gid = blockIdx.x * 256 + threadIdx.x;
    int n = gid & 7;
    int t = (gid >> 3) & 32767;
    int which = gid >> 18;
    const ushort_t* T = (which ? K : Q) + (size_t)t * 128;
    int h = (t >> 10) & 15;
    const float* P = posn + (size_t)(h * 8 + n) * 128;
    const float* Dr = dirn + (size_t)(h * 8 + n) * 128;
    float tsq = 0.f, tp = 0.f, td = 0.f;
#pragma unroll
    for (int d = 0; d < 128; d += 8) {
        uint4 raw = *(const uint4*)(T + d);
        float tv[8];
        tv[0] = __uint_as_float(raw.x << 16); tv[1] = __uint_as_float(raw.x & 0xffff0000u);
        tv[2] = __uint_as_float(raw.y << 16); tv[3] = __uint_as_float(raw.y & 0xffff0000u);
        tv[4] = __uint_as_float(raw.z << 16); tv[5] = __uint_as_float(raw.z & 0xffff0000u);
        tv[6] = __uint_as_float(raw.w << 16); tv[7] = __uint_as_float(raw.w & 0xffff0000u);
        float4 p0 = *(const float4*)(P + d), p1 = *(const float4*)(P + d + 4);
        float4 d0 = *(const float4*)(Dr + d), d1 = *(const float4*)(Dr + d + 4);
        tsq += tv[0]*tv[0]+tv[1]*tv[1]+tv[2]*tv[2]+tv[3]*tv[3]+tv[4]*tv[4]+tv[5]*tv[5]+tv[6]*tv[6]+tv[7]*tv[7];
        tp  += tv[0]*p0.x+tv[1]*p0.y+tv[2]*p0.z+tv[3]*p0.w+tv[4]*p1.x+tv[5]*p1.y+tv[6]*p1.z+tv[7]*p1.w;
        td  += tv[0]*d0.x+tv[1]*d0.y+tv[2]*d0.z+tv[3]*d0.w+tv[4]*d1.x+tv[5]*d1.y+tv[6]*d1.z+tv[7]*d1.w;
    }
    float dist2 = fmaxf(tsq - 2.f * tp + pos_sq[h * 8 + n], 0.f);
    float proj = td - pdv[h * 8 + n];
    float perp2 = fmaxf(dist2 - proj * proj, 0.f);
    float iv = iv2s2[h * 8 + n];
    float dsv = 1.f / (1.f + __expf(-ds_in[0]));
    float aff = (1.f - dsv) * __expf(-dist2 * iv) + dsv * __expf(-perp2 * iv);
    (which ? ka : qa)[(size_t)t * 8 + n] = aff;
}

// ---------------------------------------------------------------------------
// kv_s1_part: partial KV/S1 over a 128-row S-chunk. grid (32 bh, 8 sc).
// KVp[((bh*8+n)*8+sc)*128+d], S1p[(bh*8+n)*8+sc].
// ---------------------------------------------------------------------------
__global__ __launch_bounds__(128) void kv_s1_part(const float* __restrict__ ka,
                                                  const ushort_t* __restrict__ V,
                                                  float* __restrict__ KVp,
                                                  float* __restrict__ S1p) {
    int bh = blockIdx.x, sc = blockIdx.y;
    int d = threadIdx.x;
    const float* kaB = ka + ((size_t)bh * 1024 + sc * 128) * 8;
    const ushort_t* VB = V + ((size_t)bh * 1024 + sc * 128) * 128;
    float acc[8] = {};
#pragma unroll 4
    for (int s = 0; s < 128; ++s) {
        float vd = b2f(VB[(size_t)s * 128 + d]);
        float4 k0 = *(const float4*)(kaB + (size_t)s * 8);
        float4 k1 = *(const float4*)(kaB + (size_t)s * 8 + 4);
        acc[0] += k0.x * vd; acc[1] += k0.y * vd; acc[2] += k0.z * vd; acc[3] += k0.w * vd;
        acc[4] += k1.x * vd; acc[5] += k1.y * vd; acc[6] += k1.z * vd; acc[7] += k1.w * vd;
    }
#pragma unroll
    for (int n = 0; n < 8; ++n) KVp[(((size_t)bh * 8 + n) * 8 + sc) * 128 + d] = acc[n];
    __shared__ float s1p[128];
    {
        int n = d >> 4, chunk = d & 15;
        float p = 0.f;
        for (int s = chunk * 8; s < chunk * 8 + 8; ++s) p += kaB[(size_t)s * 8 + n];
        s1p[d] = p;
    }
    __syncthreads();
    if (d < 8) {
        float t = 0.f;
        for (int c = 0; c < 16; ++c) t += s1p[(d << 4) + c];
        S1p[((size_t)bh * 8 + d) * 8 + sc] = t;
    }
}

// ---------------------------------------------------------------------------
// flash_blend: grid (16 qt, 32 bh), 256 thr. 64 Q-rows/block (16/wave), K-tile
// 64, double-buffered K/V staging with ONE barrier per iteration (prefetch of
// tile kt+1 issued right after barrier kt overlaps compute kt). Q frags in
// registers. Ps is wave-private (no barrier). Blended output -> bf16 [B,S,HID].
// ---------------------------------------------------------------------------
__global__ __launch_bounds__(256) void flash_blend(
    const ushort_t* __restrict__ Qg, const ushort_t* __restrict__ Kg,
    const ushort_t* __restrict__ Vtg,
    const float* __restrict__ qa, const float* __restrict__ amp,
    const float* __restrict__ S1p, const float* __restrict__ KVp,
    const float* __restrict__ gstr, ushort_t* __restrict__ blended) {
    __shared__ ushort_t Ks[2][64 * 128];   // [key][d]    16 KB x2
    __shared__ ushort_t Vt[2][128 * 64];   // [d][key]    16 KB x2
    __shared__ ushort_t Ps[4][16 * 72];    // per wave [qrow][key], pad 72
    __shared__ float KVs[8 * 128];
    __shared__ float S1s[8];
    const int tid = threadIdx.x, lane = tid & 63, wave = tid >> 6;
    const int l15 = lane & 15, quad = lane >> 4;
    const int bh = blockIdx.y, qt = blockIdx.x;
    const float qscale = 0.08838834764831845f;  // 1/sqrt(128)

    // Q fragments straight to registers
    const ushort_t* Qrow = Qg + ((size_t)(bh * 1024 + qt * 64 + wave * 16 + l15)) * 128 + quad * 8;
    bf16x8 aq[4];
#pragma unroll
    for (int k4 = 0; k4 < 4; ++k4) aq[k4] = *(const bf16x8*)(Qrow + k4 * 32);

    // reduce KV partials (8 s-chunks) into LDS
    {
        int n = tid >> 5, d = (tid & 31) * 4;
        f32x4 kv = {};
#pragma unroll
        for (int sc = 0; sc < 8; ++sc)
            kv += *(const f32x4*)(KVp + (((size_t)bh * 8 + n) * 8 + sc) * 128 + d);
        *(f32x4*)(KVs + tid * 4) = kv;
    }
    if (tid < 8) {
        float s = 0.f;
#pragma unroll
        for (int sc = 0; sc < 8; ++sc) s += S1p[((size_t)bh * 8 + tid) * 8 + sc];
        S1s[tid] = s;
    }

    const ushort_t* Kbase = Kg + (size_t)bh * 131072;
    const ushort_t* Vbase = Vtg + (size_t)bh * 131072;

#define STAGE(buf, kt_)                                                              \
    {                                                                                \
        _Pragma("unroll") for (int i_ = 0; i_ < 4; ++i_) {                           \
            int off_ = tid * 16 + i_ * 4096;                                         \
            async_copy16((const char*)Kbase + (size_t)(kt_)*16384 + off_,            \
                         (char*)(&Ks[buf][0]) + off_);                               \
            int drow_ = off_ >> 7, ch_ = (off_ >> 4) & 7;                            \
            async_copy16(Vbase + (size_t)drow_ * 1024 + (kt_)*64 + ch_ * 8,          \
                         (char*)(&Vt[buf][0]) + off_);                               \
        }                                                                            \
    }

    STAGE(0, 0);

    f32x4 o[8] = {};
    float m_i[4] = {-INFINITY, -INFINITY, -INFINITY, -INFINITY};
    float l_i[4] = {};
    ushort_t* Pw = &Ps[wave][0];

    for (int kt = 0; kt < 16; ++kt) {
        __syncthreads();  // staging for kt complete; all waves done with buf[(kt+1)&1]
        if (kt < 15) STAGE((kt + 1) & 1, kt + 1);
        const int cb = kt & 1;
        // QK^T: 16 q-rows x 64 keys per wave
        f32x4 sc[4] = {};
#pragma unroll
        for (int k4 = 0; k4 < 4; ++k4) {
#pragma unroll
            for (int t = 0; t < 4; ++t) {
                bf16x8 bk = *(const bf16x8*)((const char*)&Ks[cb][0] +
                                             ((t * 16 + l15) * 128 + k4 * 32 + quad * 8) * 2);
                sc[t] = __builtin_amdgcn_mfma_f32_16x16x32_bf16(aq[k4], bk, sc[t], 0, 0, 0);
            }
        }
        float corr[4];
#pragma unroll
        for (int r = 0; r < 4; ++r) {
            float s0 = sc[0][r] * qscale, s1 = sc[1][r] * qscale;
            float s2 = sc[2][r] * qscale, s3 = sc[3][r] * qscale;
            float mx = fmaxf(fmaxf(s0, s1), fmaxf(s2, s3));
            mx = fmaxf(mx, __shfl_xor(mx, 1));
            mx = fmaxf(mx, __shfl_xor(mx, 2));
            mx = fmaxf(mx, __shfl_xor(mx, 4));
            mx = fmaxf(mx, __shfl_xor(mx, 8));
            float mn = fmaxf(m_i[r], mx);
            float c = __expf(m_i[r] - mn);
            float p0 = __expf(s0 - mn), p1 = __expf(s1 - mn);
            float p2 = __expf(s2 - mn), p3 = __expf(s3 - mn);
            float rs = p0 + p1 + p2 + p3;
            rs += __shfl_xor(rs, 1);
            rs += __shfl_xor(rs, 2);
            rs += __shfl_xor(rs, 4);
            rs += __shfl_xor(rs, 8);
            l_i[r] = l_i[r] * c + rs;
            m_i[r] = mn;
            corr[r] = c;
            Pw[(quad * 4 + r) * 72 + l15] = f2b(p0);
            Pw[(quad * 4 + r) * 72 + 16 + l15] = f2b(p1);
            Pw[(quad * 4 + r) * 72 + 32 + l15] = f2b(p2);
            Pw[(quad * 4 + r) * 72 + 48 + l15] = f2b(p3);
        }
#pragma unroll
        for (int j = 0; j < 8; ++j) {
            o[j][0] *= corr[0]; o[j][1] *= corr[1];
            o[j][2] *= corr[2]; o[j][3] *= corr[3];
        }
        // PV: P (16x64) @ V (64x128); Ps is wave-private, no barrier needed
        bf16x8 ap0 = *(const bf16x8*)((const char*)Pw + (l15 * 72 + quad * 8) * 2);
        bf16x8 ap1 = *(const bf16x8*)((const char*)Pw + (l15 * 72 + 32 + quad * 8) * 2);
#pragma unroll
        for (int j = 0; j < 8; ++j) {
            bf16x8 bv0 = *(const bf16x8*)((const char*)&Vt[cb][0] + ((j * 16 + l15) * 64 + quad * 8) * 2);
            bf16x8 bv1 = *(const bf16x8*)((const char*)&Vt[cb][0] + ((j * 16 + l15) * 64 + 32 + quad * 8) * 2);
            o[j] = __builtin_amdgcn_mfma_f32_16x16x32_bf16(ap0, bv0, o[j], 0, 0, 0);
            o[j] = __builtin_amdgcn_mfma_f32_16x16x32_bf16(ap1, bv1, o[j], 0, 0, 0);
        }
    }
#undef STAGE
    // epilogue
    float gsa = 1.f / (1.f + __expf(-gstr[0]));
    float blend = fminf(0.05f, gsa * 0.1f);
    int b = bh >> 4, h = bh & 15;
#pragma unroll
    for (int r = 0; r < 4; ++r) {
        int q = qt * 64 + wave * 16 + quad * 4 + r;
        const float* qaRow = qa + ((size_t)bh * 1024 + q) * 8;
        float qam[8], Z = 0.f;
#pragma unroll
        for (int n = 0; n < 8; ++n) {
            qam[n] = qaRow[n] * amp[h * 8 + n];
            Z += qam[n] * S1s[n];
        }
        float invZ = 1.f / (Z + 1e-8f);
        float invl = 1.f / l_i[r];
        ushort_t* outp = blended + ((size_t)(b * 1024 + q)) * 2048 + h * 128;
#pragma unroll
        for (int j = 0; j < 8; ++j) {
            int d = j * 16 + l15;
            float dg = 0.f;
#pragma unroll
            for (int n = 0; n < 8; ++n) dg += qam[n] * KVs[n * 128 + d];
            float v = (1.f - blend) * (o[j][r] * invl) + blend * (dg * invZ);
            outp[d] = f2b(v);
        }
    }
}

// ---------------------------------------------------------------------------
extern "C" void kernel_launch(void* const* d_in, const int* in_sizes, int n_in,
                              void* d_out, int out_size, void* d_ws, size_t ws_size,
                              hipStream_t stream) {
    const float* X = (const float*)d_in[0];
    const float* Wq = (const float*)d_in[1];
    const float* Wk = (const float*)d_in[2];
    const float* Wv = (const float*)d_in[3];
    const float* Wo = (const float*)d_in[4];
    const float* sp = (const float*)d_in[5];
    const float* sd = (const float*)d_in[6];
    const float* ls = (const float*)d_in[7];
    const float* la = (const float*)d_in[8];
    const float* dstr = (const float*)d_in[9];
    const float* gstr = (const float*)d_in[10];

    char* base = (char*)d_ws;
    ushort_t* WT3 = (ushort_t*)base;      base += 25165824;  // 3 x 2048^2 bf16
    ushort_t* Xbf = (ushort_t*)base;      base += 8388608;   // overlaid: blended
    ushort_t* blended = Xbf;                                 // Xbf dead after gemm_qkv
    ushort_t* Qbf = (ushort_t*)base;      base += 8388608;
    ushort_t* Kbf = (ushort_t*)base;      base += 8388608;
    ushort_t* Vbf = (ushort_t*)base;      base += 8388608;
    ushort_t* Vtb = (ushort_t*)base;      base += 8388608;
    float* qaw = (float*)base;            base += 1048576;
    float* kaw = (float*)base;            base += 1048576;
    float* posn = (float*)base;           base += 65536;
    float* dirn = (float*)base;           base += 65536;
    float* pos_sq = (float*)base;         base += 512;
    float* pdv = (float*)base;            base += 512;
    float* iv2s2 = (float*)base;          base += 512;
    float* ampw = (float*)base;           base += 512;
    float* S1p = (float*)base;            base += 8192;
    float* KVp = (float*)base;            base += 1048576;

    splat_prep<<<1, 128, 0, stream>>>(sp, sd, ls, la, posn, dirn, pos_sq, pdv, iv2s2, ampw);
    convert_x<<<4096, 256, 0, stream>>>(X, Xbf);
    transpose_w<<<dim3(64, 64), 256, 0, stream>>>(Wq, WT3);
    transpose_w<<<dim3(64, 64), 256, 0, stream>>>(Wk, WT3 + 4194304);
    transpose_w<<<dim3(64, 64), 256, 0, stream>>>(Wv, WT3 + 8388608);

    gemm_qkv<<<dim3(16, 48), 256, 0, stream>>>(Xbf, WT3, Qbf, Kbf, Vbf, Vtb);

    affinity_kernel<<<2048, 256, 0, stream>>>(Qbf, Kbf, posn, dirn, pos_sq, pdv, iv2s2, dstr, qaw, kaw);
    kv_s1_part<<<dim3(32, 8), 128, 0, stream>>>(kaw, Vbf, KVp, S1p);

    transpose_w<<<dim3(64, 64), 256, 0, stream>>>(Wo, WT3);  // reuse slot 0 (Wq WT dead)

    flash_blend<<<dim3(16, 32), 256, 0, stream>>>(Qbf, Kbf, Vtb, qaw, ampw, S1p, KVp, gstr, blended);
    gemm_out<<<dim3(16, 32), 256, 0, stream>>>(blended, WT3, (float*)d_out);
}

// Round 4
// 366.256 us; speedup vs baseline: 4.8843x; 1.1147x over previous
//
#include <hip/hip_runtime.h>
#include <math.h>

typedef __attribute__((ext_vector_type(8))) short bf16x8;
typedef __attribute__((ext_vector_type(4))) float f32x4;
typedef unsigned short ushort_t;

__device__ __forceinline__ unsigned short f2b(float f) {
    unsigned u = __float_as_uint(f);
    unsigned r = (u + 0x7fffu + ((u >> 16) & 1u)) >> 16;
    return (unsigned short)r;
}
__device__ __forceinline__ float b2f(unsigned short h) {
    return __uint_as_float(((unsigned)h) << 16);
}

__device__ __forceinline__ void async_copy16(const void* g, void* l) {
    __builtin_amdgcn_global_load_lds((const __attribute__((address_space(1))) void*)g,
                                     (__attribute__((address_space(3))) void*)l, 16, 0, 0);
}

// ---------------------------------------------------------------------------
// splat_prep: normalize positions/directions, precompute constants.
// ---------------------------------------------------------------------------
__global__ void splat_prep(const float* __restrict__ sp, const float* __restrict__ sd,
                           const float* __restrict__ ls, const float* __restrict__ la,
                           float* __restrict__ posn, float* __restrict__ dirn,
                           float* __restrict__ pos_sq, float* __restrict__ pdv,
                           float* __restrict__ iv2s2, float* __restrict__ amp) {
    int i = threadIdx.x;  // 0..127
    const float* p = sp + (size_t)i * 128;
    const float* d = sd + (size_t)i * 128;
    float np_ = 0.f, nd_ = 0.f;
    for (int k = 0; k < 128; ++k) { np_ += p[k] * p[k]; nd_ += d[k] * d[k]; }
    np_ = sqrtf(np_); nd_ = sqrtf(nd_);
    const float sc = 3.394112549695428f;  // sqrt(128)*0.3
    float rp = sc / (np_ + 1e-12f);
    float rd = 1.f / (nd_ + 1e-12f);
    float psq = 0.f, pd_ = 0.f;
    for (int k = 0; k < 128; ++k) {
        float pn = p[k] * rp;
        float dn = d[k] * rd;
        posn[(size_t)i * 128 + k] = pn;
        dirn[(size_t)i * 128 + k] = dn;
        psq += pn * pn;
        pd_ += pn * dn;
    }
    pos_sq[i] = psq;
    pdv[i] = pd_;
    float s = expf(ls[i]);
    s = fminf(fmaxf(s, 0.3f), 1.2f);
    iv2s2[i] = 0.5f / (s * s);
    if ((i & 7) == 0) {
        int h = i >> 3;
        float mx = -INFINITY;
        for (int n = 0; n < 8; ++n) mx = fmaxf(mx, la[h * 8 + n]);
        float e[8]; float ssum = 0.f;
        for (int n = 0; n < 8; ++n) { e[n] = expf(la[h * 8 + n] - mx); ssum += e[n]; }
        for (int n = 0; n < 8; ++n) amp[h * 8 + n] = e[n] / ssum;
    }
}

// ---------------------------------------------------------------------------
// convert_x: fp32 [2048*2048] -> bf16.
// ---------------------------------------------------------------------------
__global__ __launch_bounds__(256) void convert_x(const float* __restrict__ X,
                                                 ushort_t* __restrict__ Y) {
    int i = (blockIdx.x * 256 + threadIdx.x) * 4;
    float4 v = *(const float4*)(X + i);
    ushort4 o;
    o.x = f2b(v.x); o.y = f2b(v.y); o.z = f2b(v.z); o.w = f2b(v.w);
    *(ushort4*)(Y + i) = o;
}

// ---------------------------------------------------------------------------
// transpose_all: WT4[z][n][k] = bf16(W_z[k][n]), z in {q,k,v,o}.
// ---------------------------------------------------------------------------
__global__ __launch_bounds__(256) void transpose_all(const float* __restrict__ W0,
                                                     const float* __restrict__ W1,
                                                     const float* __restrict__ W2,
                                                     const float* __restrict__ W3,
                                                     ushort_t* __restrict__ WT4) {
    __shared__ float t[32][33];
    int z = blockIdx.z;
    const float* W = (z == 0) ? W0 : (z == 1) ? W1 : (z == 2) ? W2 : W3;
    ushort_t* WT = WT4 + (size_t)z * 4194304;
    int tx = threadIdx.x & 31, ty = threadIdx.x >> 5;
    int bn = blockIdx.x * 32, bk = blockIdx.y * 32;
#pragma unroll
    for (int i = 0; i < 4; ++i)
        t[ty + i * 8][tx] = W[(size_t)(bk + ty + i * 8) * 2048 + bn + tx];
    __syncthreads();
#pragma unroll
    for (int i = 0; i < 4; ++i)
        WT[(size_t)(bn + ty + i * 8) * 2048 + bk + tx] = f2b(t[tx][ty + i * 8]);
}

// LDS chunk swizzle for 64 B rows (4x16B chunks): phys = c ^ ((r + (r>>2)) & 3)
// spreads the 16-lane MFMA fragment reads to 2-way (free) instead of 8-way.

// ---------------------------------------------------------------------------
// gemm_qkv: fused Q/K/V projection. grid (16, 48); blockIdx.y>>4 selects the
// weight (WT4 = [Wq^T;Wk^T;Wv^T;Wo^T]). 128x128 tile, BK=32, swizzled LDS.
// Q scaled by 1/sqrt(D) at write. V also written transposed [b,h,d,s].
// ---------------------------------------------------------------------------
__global__ __launch_bounds__(256) void gemm_qkv(const ushort_t* __restrict__ A,
                                                const ushort_t* __restrict__ WT4,
                                                ushort_t* __restrict__ Qb,
                                                ushort_t* __restrict__ Kb,
                                                ushort_t* __restrict__ Vb,
                                                ushort_t* __restrict__ Vt) {
    __shared__ ushort_t As[128 * 32];
    __shared__ ushort_t Bs[128 * 32];
    const int tid = threadIdx.x, lane = tid & 63, wave = tid >> 6;
    const int l15 = lane & 15, quad = lane >> 4;
    const int wm = (wave >> 1) * 64, wn = (wave & 1) * 64;
    const int bm = blockIdx.x * 128;
    const int by = blockIdx.y, which = by >> 4, bn = (by & 15) * 128;
    const ushort_t* BT = WT4 + (size_t)which * 4194304;
    f32x4 acc[4][4] = {};
    const int off0 = tid * 16;                 // LDS byte dest
    const int row0 = tid >> 2;                 // 0..63
    const int c0 = (tid & 3) ^ ((row0 + (row0 >> 2)) & 3);  // logical src chunk
    const ushort_t* ga = A + (size_t)(bm + row0) * 2048 + c0 * 8;
    const ushort_t* gb = BT + (size_t)(bn + row0) * 2048 + c0 * 8;
    const int rsw = (l15 + (l15 >> 2)) & 3;    // read-side swizzle key
    for (int k0 = 0; k0 < 2048; k0 += 32) {
        __syncthreads();
        async_copy16(ga + k0, (char*)As + off0);
        async_copy16(ga + (size_t)64 * 2048 + k0, (char*)As + off0 + 4096);
        async_copy16(gb + k0, (char*)Bs + off0);
        async_copy16(gb + (size_t)64 * 2048 + k0, (char*)Bs + off0 + 4096);
        __syncthreads();
        bf16x8 af[4], bfr[4];
#pragma unroll
        for (int i = 0; i < 4; ++i)
            af[i] = *(const bf16x8*)((const char*)As + (wm + i * 16 + l15) * 64 + ((quad ^ rsw) << 4));
#pragma unroll
        for (int j = 0; j < 4; ++j)
            bfr[j] = *(const bf16x8*)((const char*)Bs + (wn + j * 16 + l15) * 64 + ((quad ^ rsw) << 4));
#pragma unroll
        for (int i = 0; i < 4; ++i)
#pragma unroll
            for (int j = 0; j < 4; ++j)
                acc[i][j] = __builtin_amdgcn_mfma_f32_16x16x32_bf16(af[i], bfr[j], acc[i][j], 0, 0, 0);
    }
    ushort_t* Cb = (which == 0) ? Qb : ((which == 1) ? Kb : Vb);
    const bool dot = (which == 2);
    const float oscale = (which == 0) ? 0.08838834764831845f : 1.f;  // fold 1/sqrt(D) into Q
#pragma unroll
    for (int i = 0; i < 4; ++i) {
#pragma unroll
        for (int j = 0; j < 4; ++j) {
            int m0 = bm + wm + i * 16 + quad * 4;
            int n = bn + wn + j * 16 + l15;
            int b = m0 >> 10, s0 = m0 & 1023, h = n >> 7, d = n & 127;
            ushort4 pack;
            unsigned short* pp = (unsigned short*)&pack;
#pragma unroll
            for (int r = 0; r < 4; ++r) {
                unsigned short bv = f2b(acc[i][j][r] * oscale);
                pp[r] = bv;
                Cb[((size_t)((b << 4) | h) * 1024 + (s0 + r)) * 128 + d] = bv;
            }
            if (dot) *(ushort4*)(Vt + ((size_t)((b << 4) | h) * 128 + d) * 1024 + s0) = pack;
        }
    }
}

// ---------------------------------------------------------------------------
// gemm_out: C(fp32) = A(bf16) @ BT^T. 128x64 tile -> grid (16,32), swizzled LDS.
// ---------------------------------------------------------------------------
__global__ __launch_bounds__(256) void gemm_out(const ushort_t* __restrict__ A,
                                                const ushort_t* __restrict__ BT,
                                                float* __restrict__ Cf) {
    __shared__ ushort_t As[128 * 32];
    __shared__ ushort_t Bs[64 * 32];
    const int tid = threadIdx.x, lane = tid & 63, wave = tid >> 6;
    const int l15 = lane & 15, quad = lane >> 4;
    const int wm = (wave >> 1) * 64, wn = (wave & 1) * 32;
    const int bm = blockIdx.x * 128, bn = blockIdx.y * 64;
    f32x4 acc[4][2] = {};
    const int off0 = tid * 16;
    const int row0 = tid >> 2;
    const int c0 = (tid & 3) ^ ((row0 + (row0 >> 2)) & 3);
    const ushort_t* ga = A + (size_t)(bm + row0) * 2048 + c0 * 8;
    const ushort_t* gb = BT + (size_t)(bn + row0) * 2048 + c0 * 8;
    const int rsw = (l15 + (l15 >> 2)) & 3;
    for (int k0 = 0; k0 < 2048; k0 += 32) {
        __syncthreads();
        async_copy16(ga + k0, (char*)As + off0);
        async_copy16(ga + (size_t)64 * 2048 + k0, (char*)As + off0 + 4096);
        async_copy16(gb + k0, (char*)Bs + off0);
        __syncthreads();
        bf16x8 af[4], bfr[2];
#pragma unroll
        for (int i = 0; i < 4; ++i)
            af[i] = *(const bf16x8*)((const char*)As + (wm + i * 16 + l15) * 64 + ((quad ^ rsw) << 4));
#pragma unroll
        for (int j = 0; j < 2; ++j)
            bfr[j] = *(const bf16x8*)((const char*)Bs + (wn + j * 16 + l15) * 64 + ((quad ^ rsw) << 4));
#pragma unroll
        for (int i = 0; i < 4; ++i)
#pragma unroll
            for (int j = 0; j < 2; ++j)
                acc[i][j] = __builtin_amdgcn_mfma_f32_16x16x32_bf16(af[i], bfr[j], acc[i][j], 0, 0, 0);
    }
#pragma unroll
    for (int i = 0; i < 4; ++i)
#pragma unroll
        for (int j = 0; j < 2; ++j)
#pragma unroll
            for (int r = 0; r < 4; ++r) {
                int m = bm + wm + i * 16 + quad * 4 + r;
                int n = bn + wn + j * 16 + l15;
                Cf[(size_t)m * 2048 + n] = acc[i][j][r];
            }
}

// ---------------------------------------------------------------------------
// affinity: qa/ka [B,NH,S,NS] fp32. Q is pre-scaled by 1/sqrt(D): compensate.
// ---------------------------------------------------------------------------
__global__ __launch_bounds__(256) void affinity_kernel(
    const ushort_t* __restrict__ Q, const ushort_t* __restrict__ K,
    const float* __restrict__ posn, const float* __restrict__ dirn,
    const float* __restrict__ pos_sq, const float* __restrict__ pdv,
    const float* __restrict__ iv2s2, const float* __restrict__ ds_in,
    float* __restrict__ qa, float* __restrict__ ka) {
    int gid = blockIdx.x * 256 + threadIdx.x;
    int n = gid & 7;
    int t = (gid >> 3) & 32767;
    int which = gid >> 18;
    const ushort_t* T = (which ? K : Q) + (size_t)t * 128;
    int h = (t >> 10) & 15;
    const float* P = posn + (size_t)(h * 8 + n) * 128;
    const float* Dr = dirn + (size_t)(h * 8 + n) * 128;
    float tsq = 0.f, tp = 0.f, td = 0.f;
#pragma unroll
    for (int d = 0; d < 128; d += 8) {
        uint4 raw = *(const uint4*)(T + d);
        float tv[8];
        tv[0] = __uint_as_float(raw.x << 16); tv[1] = __uint_as_float(raw.x & 0xffff0000u);
        tv[2] = __uint_as_float(raw.y << 16); tv[3] = __uint_as_float(raw.y & 0xffff0000u);
        tv[4] = __uint_as_float(raw.z << 16); tv[5] = __uint_as_float(raw.z & 0xffff0000u);
        tv[6] = __uint_as_float(raw.w << 16); tv[7] = __uint_as_float(raw.w & 0xffff0000u);
        float4 p0 = *(const float4*)(P + d), p1 = *(const float4*)(P + d + 4);
        float4 d0 = *(const float4*)(Dr + d), d1 = *(const float4*)(Dr + d + 4);
        tsq += tv[0]*tv[0]+tv[1]*tv[1]+tv[2]*tv[2]+tv[3]*tv[3]+tv[4]*tv[4]+tv[5]*tv[5]+tv[6]*tv[6]+tv[7]*tv[7];
        tp  += tv[0]*p0.x+tv[1]*p0.y+tv[2]*p0.z+tv[3]*p0.w+tv[4]*p1.x+tv[5]*p1.y+tv[6]*p1.z+tv[7]*p1.w;
        td  += tv[0]*d0.x+tv[1]*d0.y+tv[2]*d0.z+tv[3]*d0.w+tv[4]*d1.x+tv[5]*d1.y+tv[6]*d1.z+tv[7]*d1.w;
    }
    float fs = which ? 1.f : 11.313708498984761f;  // undo 1/sqrt(D) on Q
    tsq *= fs * fs; tp *= fs; td *= fs;
    float dist2 = fmaxf(tsq - 2.f * tp + pos_sq[h * 8 + n], 0.f);
    float proj = td - pdv[h * 8 + n];
    float perp2 = fmaxf(dist2 - proj * proj, 0.f);
    float iv = iv2s2[h * 8 + n];
    float dsv = 1.f / (1.f + __expf(-ds_in[0]));
    float aff = (1.f - dsv) * __expf(-dist2 * iv) + dsv * __expf(-perp2 * iv);
    (which ? ka : qa)[(size_t)t * 8 + n] = aff;
}

// ---------------------------------------------------------------------------
// kv_s1_part: partial KV/S1 over a 128-row S-chunk. grid (32 bh, 8 sc).
// ---------------------------------------------------------------------------
__global__ __launch_bounds__(128) void kv_s1_part(const float* __restrict__ ka,
                                                  const ushort_t* __restrict__ V,
                                                  float* __restrict__ KVp,
                                                  float* __restrict__ S1p) {
    int bh = blockIdx.x, sc = blockIdx.y;
    int d = threadIdx.x;
    const float* kaB = ka + ((size_t)bh * 1024 + sc * 128) * 8;
    const ushort_t* VB = V + ((size_t)bh * 1024 + sc * 128) * 128;
    float acc[8] = {};
#pragma unroll 4
    for (int s = 0; s < 128; ++s) {
        float vd = b2f(VB[(size_t)s * 128 + d]);
        float4 k0 = *(const float4*)(kaB + (size_t)s * 8);
        float4 k1 = *(const float4*)(kaB + (size_t)s * 8 + 4);
        acc[0] += k0.x * vd; acc[1] += k0.y * vd; acc[2] += k0.z * vd; acc[3] += k0.w * vd;
        acc[4] += k1.x * vd; acc[5] += k1.y * vd; acc[6] += k1.z * vd; acc[7] += k1.w * vd;
    }
#pragma unroll
    for (int n = 0; n < 8; ++n) KVp[(((size_t)bh * 8 + n) * 8 + sc) * 128 + d] = acc[n];
    __shared__ float s1p[128];
    {
        int n = d >> 4, chunk = d & 15;
        float p = 0.f;
        for (int s = chunk * 8; s < chunk * 8 + 8; ++s) p += kaB[(size_t)s * 8 + n];
        s1p[d] = p;
    }
    __syncthreads();
    if (d < 8) {
        float t = 0.f;
        for (int c = 0; c < 16; ++c) t += s1p[(d << 4) + c];
        S1p[((size_t)bh * 8 + d) * 8 + sc] = t;
    }
}

// ---------------------------------------------------------------------------
// flash_blend: grid (16 qt, 32 bh). 64 Q-rows/block, K-tile 64, double-buffered
// swizzled K/V staging, one barrier/iter. No max-tracking softmax (scores
// provably bounded ~|17|): l_i is lane-local, reduced once at end. Q pre-scaled.
// ---------------------------------------------------------------------------
__global__ __launch_bounds__(256) void flash_blend(
    const ushort_t* __restrict__ Qg, const ushort_t* __restrict__ Kg,
    const ushort_t* __restrict__ Vtg,
    const float* __restrict__ qa, const float* __restrict__ amp,
    const float* __restrict__ S1p, const float* __restrict__ KVp,
    const float* __restrict__ gstr, ushort_t* __restrict__ blended) {
    __shared__ ushort_t Ks[2][64 * 128];   // [key][d], 16B chunks swizzled ^ (key&15)
    __shared__ ushort_t Vt[2][128 * 64];   // [d][key], 16B chunks swizzled ^ (d&7)
    __shared__ ushort_t Ps[4][16 * 72];    // wave-private [qrow][key], pad 72
    __shared__ float KVs[8 * 128];
    __shared__ float S1s[8];
    const int tid = threadIdx.x, lane = tid & 63, wave = tid >> 6;
    const int l15 = lane & 15, quad = lane >> 4;
    const int bh = blockIdx.y, qt = blockIdx.x;

    const ushort_t* Qrow = Qg + ((size_t)(bh * 1024 + qt * 64 + wave * 16 + l15)) * 128 + quad * 8;
    bf16x8 aq[4];
#pragma unroll
    for (int k4 = 0; k4 < 4; ++k4) aq[k4] = *(const bf16x8*)(Qrow + k4 * 32);

    {
        int n = tid >> 5, d = (tid & 31) * 4;
        f32x4 kv = {};
#pragma unroll
        for (int sc = 0; sc < 8; ++sc)
            kv += *(const f32x4*)(KVp + (((size_t)bh * 8 + n) * 8 + sc) * 128 + d);
        *(f32x4*)(KVs + tid * 4) = kv;
    }
    if (tid < 8) {
        float s = 0.f;
#pragma unroll
        for (int sc = 0; sc < 8; ++sc) s += S1p[((size_t)bh * 8 + tid) * 8 + sc];
        S1s[tid] = s;
    }

    const ushort_t* Kbase = Kg + (size_t)bh * 131072;
    const ushort_t* Vbase = Vtg + (size_t)bh * 131072;

    // staging with swizzle: K dest (r,p) <- src chunk p^(r&15); V (d,p) <- p^(d&7)
#define STAGE(buf, kt_)                                                               \
    {                                                                                 \
        _Pragma("unroll") for (int i_ = 0; i_ < 4; ++i_) {                            \
            int off_ = tid * 16 + i_ * 4096;                                          \
            int kr_ = off_ >> 8, kp_ = (off_ >> 4) & 15;                              \
            async_copy16(Kbase + (size_t)(kt_)*8192 + kr_ * 128 + ((kp_ ^ (kr_ & 15)) << 3), \
                         (char*)(&Ks[buf][0]) + off_);                                \
            int vd_ = off_ >> 7, vp_ = (off_ >> 4) & 7;                               \
            async_copy16(Vbase + (size_t)vd_ * 1024 + (kt_)*64 + ((vp_ ^ (vd_ & 7)) << 3), \
                         (char*)(&Vt[buf][0]) + off_);                                \
        }                                                                             \
    }

    STAGE(0, 0);

    f32x4 o[8] = {};
    float l_i[4] = {};
    ushort_t* Pw = &Ps[wave][0];

    for (int kt = 0; kt < 16; ++kt) {
        __syncthreads();
        if (kt < 15) STAGE((kt + 1) & 1, kt + 1);
        const int cb = kt & 1;
        // QK^T: 16 q-rows x 64 keys per wave (Q pre-scaled by 1/sqrt(D))
        f32x4 sc[4] = {};
#pragma unroll
        for (int k4 = 0; k4 < 4; ++k4) {
#pragma unroll
            for (int t = 0; t < 4; ++t) {
                bf16x8 bk = *(const bf16x8*)((const char*)&Ks[cb][0] +
                                             ((t * 16 + l15) << 8) + (((k4 * 4 + quad) ^ l15) << 4));
                sc[t] = __builtin_amdgcn_mfma_f32_16x16x32_bf16(aq[k4], bk, sc[t], 0, 0, 0);
            }
        }
        // flat exp (no max subtraction), lane-local l accumulation
#pragma unroll
        for (int t = 0; t < 4; ++t) {
#pragma unroll
            for (int r = 0; r < 4; ++r) {
                float p = __expf(sc[t][r]);
                l_i[r] += p;
                Pw[(quad * 4 + r) * 72 + t * 16 + l15] = f2b(p);
            }
        }
        // PV: P (16x64) @ V^T tiles; Ps wave-private, no barrier
        bf16x8 ap0 = *(const bf16x8*)((const char*)Pw + (l15 * 72 + quad * 8) * 2);
        bf16x8 ap1 = *(const bf16x8*)((const char*)Pw + (l15 * 72 + 32 + quad * 8) * 2);
#pragma unroll
        for (int j = 0; j < 8; ++j) {
            bf16x8 bv0 = *(const bf16x8*)((const char*)&Vt[cb][0] +
                                          ((j * 16 + l15) << 7) + (((quad) ^ (l15 & 7)) << 4));
            bf16x8 bv1 = *(const bf16x8*)((const char*)&Vt[cb][0] +
                                          ((j * 16 + l15) << 7) + (((4 + quad) ^ (l15 & 7)) << 4));
            o[j] = __builtin_amdgcn_mfma_f32_16x16x32_bf16(ap0, bv0, o[j], 0, 0, 0);
            o[j] = __builtin_amdgcn_mfma_f32_16x16x32_bf16(ap1, bv1, o[j], 0, 0, 0);
        }
    }
#undef STAGE
    // reduce l across the 16 column-lanes (l15 bits = shfl masks 1,2,4,8)
#pragma unroll
    for (int r = 0; r < 4; ++r) {
        float l = l_i[r];
        l += __shfl_xor(l, 1);
        l += __shfl_xor(l, 2);
        l += __shfl_xor(l, 4);
        l += __shfl_xor(l, 8);
        l_i[r] = l;
    }
    // epilogue
    float gsa = 1.f / (1.f + __expf(-gstr[0]));
    float blend = fminf(0.05f, gsa * 0.1f);
    int b = bh >> 4, h = bh & 15;
#pragma unroll
    for (int r = 0; r < 4; ++r) {
        int q = qt * 64 + wave * 16 + quad * 4 + r;
        const float* qaRow = qa + ((size_t)bh * 1024 + q) * 8;
        float qam[8], Z = 0.f;
#pragma unroll
        for (int n = 0; n < 8; ++n) {
            qam[n] = qaRow[n] * amp[h * 8 + n];
            Z += qam[n] * S1s[n];
        }
        float invZ = 1.f / (Z + 1e-8f);
        float invl = 1.f / l_i[r];
        ushort_t* outp = blended + ((size_t)(b * 1024 + q)) * 2048 + h * 128;
#pragma unroll
        for (int j = 0; j < 8; ++j) {
            int d = j * 16 + l15;
            float dg = 0.f;
#pragma unroll
            for (int n = 0; n < 8; ++n) dg += qam[n] * KVs[n * 128 + d];
            float v = (1.f - blend) * (o[j][r] * invl) + blend * (dg * invZ);
            outp[d] = f2b(v);
        }
    }
}

// ---------------------------------------------------------------------------
extern "C" void kernel_launch(void* const* d_in, const int* in_sizes, int n_in,
                              void* d_out, int out_size, void* d_ws, size_t ws_size,
                              hipStream_t stream) {
    const float* X = (const float*)d_in[0];
    const float* Wq = (const float*)d_in[1];
    const float* Wk = (const float*)d_in[2];
    const float* Wv = (const float*)d_in[3];
    const float* Wo = (const float*)d_in[4];
    const float* sp = (const float*)d_in[5];
    const float* sd = (const float*)d_in[6];
    const float* ls = (const float*)d_in[7];
    const float* la = (const float*)d_in[8];
    const float* dstr = (const float*)d_in[9];
    const float* gstr = (const float*)d_in[10];

    char* base = (char*)d_ws;
    ushort_t* WT4 = (ushort_t*)base;      base += 33554432;  // 4 x 2048^2 bf16
    ushort_t* Xbf = (ushort_t*)base;      base += 8388608;   // overlaid: blended
    ushort_t* blended = Xbf;                                 // Xbf dead after gemm_qkv
    ushort_t* Qbf = (ushort_t*)base;      base += 8388608;
    ushort_t* Kbf = (ushort_t*)base;      base += 8388608;
    ushort_t* Vbf = (ushort_t*)base;      base += 8388608;
    ushort_t* Vtb = (ushort_t*)base;      base += 8388608;
    float* qaw = (float*)base;            base += 1048576;
    float* kaw = (float*)base;            base += 1048576;
    float* posn = (float*)base;           base += 65536;
    float* dirn = (float*)base;           base += 65536;
    float* pos_sq = (float*)base;         base += 512;
    float* pdv = (float*)base;            base += 512;
    float* iv2s2 = (float*)base;          base += 512;
    float* ampw = (float*)base;           base += 512;
    float* S1p = (float*)base;            base += 8192;
    float* KVp = (float*)base;            base += 1048576;

    splat_prep<<<1, 128, 0, stream>>>(sp, sd, ls, la, posn, dirn, pos_sq, pdv, iv2s2, ampw);
    convert_x<<<4096, 256, 0, stream>>>(X, Xbf);
    transpose_all<<<dim3(64, 64, 4), 256, 0, stream>>>(Wq, Wk, Wv, Wo, WT4);

    gemm_qkv<<<dim3(16, 48), 256, 0, stream>>>(Xbf, WT4, Qbf, Kbf, Vbf, Vtb);

    affinity_kernel<<<2048, 256, 0, stream>>>(Qbf, Kbf, posn, dirn, pos_sq, pdv, iv2s2, dstr, qaw, kaw);
    kv_s1_part<<<dim3(32, 8), 128, 0, stream>>>(kaw, Vbf, KVp, S1p);

    flash_blend<<<dim3(16, 32), 256, 0, stream>>>(Qbf, Kbf, Vtb, qaw, ampw, S1p, KVp, gstr, blended);
    gemm_out<<<dim3(16, 32), 256, 0, stream>>>(blended, WT4 + 12582912, (float*)d_out);
}